// Round 8
// baseline (411.788 us; speedup 1.0000x reference)
//
#include <hip/hip_runtime.h>

typedef __bf16 bf16x8 __attribute__((ext_vector_type(8)));
typedef float  f32x4  __attribute__((ext_vector_type(4)));

constexpr int M_ROWS = 65536;
constexpr int N_COLS = 2048;
constexpr int K_DIM  = 512;
constexpr int BM = 128, BN = 128, BK = 32;
constexpr int NKT = K_DIM / BK;        // 16 K-steps
constexpr int MB_CNT = M_ROWS / BM;    // 512
constexpr int NB_CNT = N_COLS / BN;    // 16

constexpr size_t A_ELEMS = (size_t)M_ROWS * K_DIM;
constexpr size_t W_ELEMS = (size_t)N_COLS * K_DIM;
// packed blocks per (tile, kt): [hi 4096 ushorts][lo 4096 ushorts] = 16 KB
constexpr size_t APK_USHORTS = (size_t)MB_CNT * NKT * 8192;  // 128 MiB
constexpr size_t WPK_USHORTS = (size_t)NB_CNT * NKT * 8192;  //   4 MiB

__device__ __forceinline__ unsigned short f2bf(float f){
  unsigned int u = __float_as_uint(f);
  u += 0x7FFFu + ((u >> 16) & 1u);     // RNE
  return (unsigned short)(u >> 16);
}
__device__ __forceinline__ float bf2f(unsigned short h){
  return __uint_as_float(((unsigned int)h) << 16);
}
__device__ __forceinline__ void split4(const float4& v, ushort4& h, ushort4& l){
  h.x = f2bf(v.x); l.x = f2bf(v.x - bf2f(h.x));
  h.y = f2bf(v.y); l.y = f2bf(v.y - bf2f(h.y));
  h.z = f2bf(v.z); l.z = f2bf(v.z - bf2f(h.z));
  h.w = f2bf(v.w); l.w = f2bf(v.w - bf2f(h.w));
}
__device__ __forceinline__ void split4v(const f32x4& v, ushort4& h, ushort4& l){
  h.x = f2bf(v.x); l.x = f2bf(v.x - bf2f(h.x));
  h.y = f2bf(v.y); l.y = f2bf(v.y - bf2f(h.y));
  h.z = f2bf(v.z); l.z = f2bf(v.z - bf2f(h.z));
  h.w = f2bf(v.w); l.w = f2bf(v.w - bf2f(h.w));
}

__device__ __forceinline__ void gl_lds16(const void* g, void* l){
  __builtin_amdgcn_global_load_lds(
      (const __attribute__((address_space(1))) unsigned int*)g,
      (__attribute__((address_space(3))) unsigned int*)l, 16, 0, 0);
}

constexpr float INV2PI = 0.15915494309189535f;
__device__ __forceinline__ float cos_scaled(float v){
  float rev = v * INV2PI;
  rev -= floorf(rev);                   // [0,1) revolutions for v_cos
  return 0.03125f * __builtin_amdgcn_cosf(rev);
}

// ============ fused prepass: X->Apk (8192 blocks) + W->Wpk (1024) ===========
// 16x16x32 fragment layout.
// Apk block (mb,kt): chunk c = i*64 + q*16 + r  <->  A row mb*128+i*16+r,
// k = kt*32 + q*8..+7 (k-contiguous bf16). hi at +0, lo at +4096 ushorts.
// Wpk block (nb,kt): chunk c = (wn*4+j)*64 + q*16 + fc holds W[k=kt*32+q*8..][n],
// n = nb*128 + wn*64 + fc*4 + j  (col-perm: lane fc owns 4 consecutive cols
// per j-quad -> float4 epilogue stores).
__global__ void pack_fused(const float* __restrict__ X, const float* __restrict__ W,
                           unsigned short* __restrict__ Apk,
                           unsigned short* __restrict__ Wpk){
  __shared__ __align__(16) unsigned short lds[8192];
  const int b = blockIdx.x, t = threadIdx.x;
  if (b < MB_CNT * NKT){
    const int mb = b >> 4, kt = b & 15;
    const float* src = X + (size_t)mb * 128 * K_DIM + kt * 32;
    const int fq = t & 7, r0 = t >> 3;
    #pragma unroll
    for (int it = 0; it < 4; ++it){
      int row = r0 + it * 32;
      f32x4 v = __builtin_nontemporal_load(
          reinterpret_cast<const f32x4*>(src + (size_t)row * K_DIM + fq * 4));
      ushort4 h, l; split4v(v, h, l);
      int i = row >> 4, r = row & 15, q = fq >> 1, half = fq & 1;
      int base = (i * 64 + q * 16 + r) * 8 + half * 4;
      *reinterpret_cast<ushort4*>(lds + base)        = h;
      *reinterpret_cast<ushort4*>(lds + 4096 + base) = l;
    }
    __syncthreads();
    unsigned short* dst = Apk + ((size_t)mb * NKT + kt) * 8192;
    #pragma unroll
    for (int it = 0; it < 4; ++it){
      int c = t + it * 256;
      *reinterpret_cast<int4*>(dst + c * 8) = *reinterpret_cast<const int4*>(lds + c * 8);
    }
  } else {
    // W patch: 32 cols x 32 k.  n0 = nbx*32, k0 = kt*32.
    const int b2 = b - MB_CNT * NKT;
    const int nbx = b2 & 63, kt = b2 >> 6;
    const int n0 = nbx * 32;
    const int nb = nbx >> 2;                 // 128-col Wpk block
    float (*tf)[33] = reinterpret_cast<float(*)[33]>(lds);
    int tx = t & 31, ty = t >> 5;
    #pragma unroll
    for (int rr = 0; rr < 4; ++rr)
      tf[ty + rr*8][tx] = W[(size_t)(kt * 32 + ty + rr*8) * N_COLS + n0 + tx];
    __syncthreads();
    unsigned short* dst = Wpk + ((size_t)nb * NKT + kt) * 8192;
    const int q = tx >> 3, ko = tx & 7;
    #pragma unroll
    for (int rr = 0; rr < 4; ++rr){
      int nl = ty + rr*8;                    // local col 0..31
      float vv = tf[tx][nl];                 // W[k0+tx][n0+nl]
      unsigned short hh = f2bf(vv);
      unsigned short ll = f2bf(vv - bf2f(hh));
      int ng = (nbx & 3) * 32 + nl;          // col within 128-block
      int wn = ng >> 6, rem = ng & 63;
      int j = rem & 3, fc = rem >> 2;        // col-perm: rem = fc*4 + j
      int e = (((wn << 2) + j) * 64 + q * 16 + fc) * 8 + ko;
      dst[e] = hh; dst[4096 + e] = ll;
    }
  }
}

// ============ main GEMM + cos epilogue ======================================
// 2x2 wave grid: wave (wm,wn) owns rows [wm*64,+64) x cols [wn*64,+64).
// A: per-lane global loads (fragment-linear, no LDS), reg-dbuffed (2 sets).
// B: LDS dbuf 2x16KB via gl_lds issued at TOP of each step; 1 barrier/step.
// Per wave-step: 8 ds_read_b128 feed 48 MFMA (12 MFMA per B-frag read).
__launch_bounds__(256, 3)
__global__ void rbf_gemm_d(const unsigned short* __restrict__ Apk,
                           const unsigned short* __restrict__ Wpk,
                           const float* __restrict__ bvec,
                           float* __restrict__ out){
  __shared__ __align__(16) unsigned short smem[2 * 8192];   // 32 KB (B only)

  int orig = blockIdx.x;                       // 8192 blocks, 8192 % 8 == 0
  int wgid = (orig & 7) * 1024 + (orig >> 3);  // bijective XCD swizzle
  int mb = wgid >> 4, nb = wgid & 15;
  int m0 = mb * BM, n0 = nb * BN;

  int tid = threadIdx.x, lane = tid & 63, wid = tid >> 6;
  int wm = wid >> 1, wn = wid & 1;
  int r = lane & 15, g = lane >> 4;

  const char* abase = (const char*)(Apk + (size_t)mb * NKT * 8192);
  const char* bbase = (const char*)(Wpk + (size_t)nb * NKT * 8192);
  char* ldsb = (char*)smem;
  int aoffs[4];
  #pragma unroll
  for (int i = 0; i < 4; ++i) aoffs[i] = ((wm * 4 + i) * 64 + lane) * 16;  // bytes
  int boffs[4];
  #pragma unroll
  for (int j = 0; j < 4; ++j) boffs[j] = ((wn * 4 + j) * 64 + lane) * 8;   // ushorts
  const int bsoff = wid * 1024 + lane * 16;    // staging src lane offset
  const int bdoff = wid * 1024;                // staging dest (wave-uniform)

  f32x4 acc[4][4];
  #pragma unroll
  for (int i = 0; i < 4; ++i)
    #pragma unroll
    for (int j = 0; j < 4; ++j) acc[i][j] = (f32x4){0.f, 0.f, 0.f, 0.f};

  // A register sets (named, fully static indexing)
  bf16x8 ahA[4], alA[4], ahB[4], alB[4];

  // prologue: A[0] -> set A, B[0] -> buf0
  #pragma unroll
  for (int i = 0; i < 4; ++i){
    ahA[i] = *reinterpret_cast<const bf16x8*>(abase + aoffs[i]);
    alA[i] = *reinterpret_cast<const bf16x8*>(abase + 8192 + aoffs[i]);
  }
  #pragma unroll
  for (int it = 0; it < 4; ++it)
    gl_lds16(bbase + it * 4096 + bsoff, ldsb + it * 4096 + bdoff);
  __syncthreads();                             // B[0] ready

  #pragma unroll 1
  for (int kt = 0; kt < NKT; kt += 2){
    // ---------------- even sub-step ----------------
    {
      const unsigned short* SB = smem;                       // buf0
      // issue B[kt+1] -> buf1 at step TOP (latency spans whole step)
      const char* bb = bbase + (size_t)(kt + 1) * 16384;
      #pragma unroll
      for (int it = 0; it < 4; ++it)
        gl_lds16(bb + it * 4096 + bsoff, ldsb + 16384 + it * 4096 + bdoff);
      // prefetch A[kt+1] -> set B
      const char* ab = abase + (size_t)(kt + 1) * 16384;
      #pragma unroll
      for (int i = 0; i < 4; ++i){
        ahB[i] = *reinterpret_cast<const bf16x8*>(ab + aoffs[i]);
        alB[i] = *reinterpret_cast<const bf16x8*>(ab + 8192 + aoffs[i]);
      }
      #pragma unroll
      for (int j = 0; j < 4; ++j){
        bf16x8 bh = *reinterpret_cast<const bf16x8*>(&SB[boffs[j]]);
        bf16x8 bl = *reinterpret_cast<const bf16x8*>(&SB[boffs[j] + 4096]);
        #pragma unroll
        for (int i = 0; i < 4; ++i){
          acc[i][j] = __builtin_amdgcn_mfma_f32_16x16x32_bf16(ahA[i], bh, acc[i][j], 0, 0, 0);
          acc[i][j] = __builtin_amdgcn_mfma_f32_16x16x32_bf16(alA[i], bh, acc[i][j], 0, 0, 0);
          acc[i][j] = __builtin_amdgcn_mfma_f32_16x16x32_bf16(ahA[i], bl, acc[i][j], 0, 0, 0);
        }
      }
      __syncthreads();   // buf1 landed; all reads of buf0 done
    }
    // ---------------- odd sub-step -----------------
    {
      const unsigned short* SB = smem + 8192;                // buf1
      if (kt + 2 < NKT){
        const char* bb = bbase + (size_t)(kt + 2) * 16384;
        #pragma unroll
        for (int it = 0; it < 4; ++it)
          gl_lds16(bb + it * 4096 + bsoff, ldsb + it * 4096 + bdoff);
        const char* ab = abase + (size_t)(kt + 2) * 16384;
        #pragma unroll
        for (int i = 0; i < 4; ++i){
          ahA[i] = *reinterpret_cast<const bf16x8*>(ab + aoffs[i]);
          alA[i] = *reinterpret_cast<const bf16x8*>(ab + 8192 + aoffs[i]);
        }
      }
      #pragma unroll
      for (int j = 0; j < 4; ++j){
        bf16x8 bh = *reinterpret_cast<const bf16x8*>(&SB[boffs[j]]);
        bf16x8 bl = *reinterpret_cast<const bf16x8*>(&SB[boffs[j] + 4096]);
        #pragma unroll
        for (int i = 0; i < 4; ++i){
          acc[i][j] = __builtin_amdgcn_mfma_f32_16x16x32_bf16(ahB[i], bh, acc[i][j], 0, 0, 0);
          acc[i][j] = __builtin_amdgcn_mfma_f32_16x16x32_bf16(alB[i], bh, acc[i][j], 0, 0, 0);
          acc[i][j] = __builtin_amdgcn_mfma_f32_16x16x32_bf16(ahB[i], bl, acc[i][j], 0, 0, 0);
        }
      }
      __syncthreads();
    }
  }

  // epilogue: acc[i][j] lane(r,g) reg p -> row m0 + wm*64 + i*16 + g*4 + p,
  // col n0 + wn*64 + r*4 + j  -> nontemporal float4 stores (full lines).
  int colb = n0 + wn * 64 + r * 4;
  f32x4 bv = *reinterpret_cast<const f32x4*>(bvec + colb);
  #pragma unroll
  for (int i = 0; i < 4; ++i){
    #pragma unroll
    for (int p = 0; p < 4; ++p){
      int row = m0 + wm * 64 + i * 16 + g * 4 + p;
      f32x4 o;
      o.x = cos_scaled(acc[i][0][p] + bv.x);
      o.y = cos_scaled(acc[i][1][p] + bv.y);
      o.z = cos_scaled(acc[i][2][p] + bv.z);
      o.w = cos_scaled(acc[i][3][p] + bv.w);
      __builtin_nontemporal_store(o, reinterpret_cast<f32x4*>(out + (size_t)row * N_COLS + colb));
    }
  }
}

// ================= fallback (no workspace): 16x16 path ======================
constexpr int LDSK = 40;
constexpr int SEC  = 128 * LDSK;
__launch_bounds__(256, 2)
__global__ void rbf_gemm_nows(const float* __restrict__ X, const float* __restrict__ W,
                              const float* __restrict__ bvec, float* __restrict__ out){
  __shared__ __align__(16) unsigned short smem[4 * SEC];
  int orig = blockIdx.x;
  int wgid = (orig & 7) * (int)(gridDim.x >> 3) + (orig >> 3);
  int mb = wgid >> 4, nb = wgid & 15;
  int m0 = mb * BM, n0 = nb * BN;
  int tid = threadIdx.x, lane = tid & 63, wid = tid >> 6;
  int wm = wid >> 1, wn = wid & 1;
  int r = lane & 15, g = lane >> 4;

  const float* asrc[4]; int alofs[4]; float4 ra[4];
  const float* wsrc[4]; int wnq4[4]; int wkr[4]; float4 rw[4];
  #pragma unroll
  for (int i = 0; i < 4; ++i){
    int c = tid + i * 256;
    int row = c >> 3, q = c & 7;
    asrc[i]  = X + (size_t)(m0 + row) * K_DIM + q * 4;
    alofs[i] = row * LDSK + q * 4;
  }
  #pragma unroll
  for (int i = 0; i < 4; ++i) ra[i] = *reinterpret_cast<const float4*>(asrc[i]);
  #pragma unroll
  for (int i = 0; i < 4; ++i){
    int c = tid + i * 256;
    int kr = c >> 5, nq = c & 31;
    wsrc[i] = W + (size_t)kr * N_COLS + n0 + nq * 4;
    wkr[i] = kr; wnq4[i] = nq * 4;
  }
  #pragma unroll
  for (int i = 0; i < 4; ++i) rw[i] = *reinterpret_cast<const float4*>(wsrc[i]);

  f32x4 acc[4][4];
  f32x4 zero = {0.f, 0.f, 0.f, 0.f};
  #pragma unroll
  for (int i = 0; i < 4; ++i)
    #pragma unroll
    for (int j = 0; j < 4; ++j) acc[i][j] = zero;

  int aoff[4], boff[4];
  #pragma unroll
  for (int i = 0; i < 4; ++i) aoff[i] = (wm*64 + i*16 + r) * LDSK + g * 8;
  #pragma unroll
  for (int j = 0; j < 4; ++j) boff[j] = (wn*64 + j*16 + r) * LDSK + g * 8;

  #pragma unroll 1
  for (int kt = 0; kt < NKT; ++kt){
    __syncthreads();
    #pragma unroll
    for (int i = 0; i < 4; ++i){
      ushort4 h, l;
      split4(ra[i], h, l);
      *reinterpret_cast<ushort4*>(&smem[alofs[i]])       = h;
      *reinterpret_cast<ushort4*>(&smem[SEC + alofs[i]]) = l;
    }
    #pragma unroll
    for (int i = 0; i < 4; ++i){
      float vv[4] = {rw[i].x, rw[i].y, rw[i].z, rw[i].w};
      #pragma unroll
      for (int w2 = 0; w2 < 4; ++w2){
        unsigned short h = f2bf(vv[w2]);
        unsigned short l = f2bf(vv[w2] - bf2f(h));
        int n = wnq4[i] + w2;
        smem[2*SEC + n*LDSK + wkr[i]] = h;
        smem[3*SEC + n*LDSK + wkr[i]] = l;
      }
    }
    if (kt < NKT - 1){
      #pragma unroll
      for (int i = 0; i < 4; ++i)
        ra[i] = *reinterpret_cast<const float4*>(asrc[i] + (kt+1)*BK);
      #pragma unroll
      for (int i = 0; i < 4; ++i)
        rw[i] = *reinterpret_cast<const float4*>(wsrc[i] + (size_t)(kt+1)*BK*N_COLS);
    }
    __syncthreads();
    bf16x8 ah[4], al[4], bh[4], bl[4];
    #pragma unroll
    for (int i = 0; i < 4; ++i){
      ah[i] = *reinterpret_cast<const bf16x8*>(&smem[aoff[i]]);
      al[i] = *reinterpret_cast<const bf16x8*>(&smem[SEC + aoff[i]]);
    }
    #pragma unroll
    for (int j = 0; j < 4; ++j){
      bh[j] = *reinterpret_cast<const bf16x8*>(&smem[2*SEC + boff[j]]);
      bl[j] = *reinterpret_cast<const bf16x8*>(&smem[3*SEC + boff[j]]);
    }
    #pragma unroll
    for (int i = 0; i < 4; ++i){
      #pragma unroll
      for (int j = 0; j < 4; ++j){
        acc[i][j] = __builtin_amdgcn_mfma_f32_16x16x32_bf16(ah[i], bh[j], acc[i][j], 0, 0, 0);
        acc[i][j] = __builtin_amdgcn_mfma_f32_16x16x32_bf16(al[i], bh[j], acc[i][j], 0, 0, 0);
        acc[i][j] = __builtin_amdgcn_mfma_f32_16x16x32_bf16(ah[i], bl[j], acc[i][j], 0, 0, 0);
      }
    }
  }

  float bvv[4];
  #pragma unroll
  for (int j = 0; j < 4; ++j) bvv[j] = bvec[n0 + wn*64 + j*16 + r];
  #pragma unroll
  for (int i = 0; i < 4; ++i){
    #pragma unroll
    for (int j = 0; j < 4; ++j){
      int col = n0 + wn*64 + j*16 + r;
      #pragma unroll
      for (int p = 0; p < 4; ++p){
        int row = m0 + wm*64 + i*16 + g*4 + p;
        out[(size_t)row * N_COLS + col] = cos_scaled(acc[i][j][p] + bvv[j]);
      }
    }
  }
}

extern "C" void kernel_launch(void* const* d_in, const int* in_sizes, int n_in,
                              void* d_out, int out_size, void* d_ws, size_t ws_size,
                              hipStream_t stream){
  const float* X = (const float*)d_in[0];
  const float* W = (const float*)d_in[1];
  const float* b = (const float*)d_in[2];
  float* out = (float*)d_out;
  unsigned short* ws = (unsigned short*)d_ws;

  const size_t needP = (APK_USHORTS + WPK_USHORTS) * sizeof(unsigned short); // 132 MiB

  if (ws && ws_size >= needP){
    unsigned short* Apk = ws;
    unsigned short* Wpk = ws + APK_USHORTS;
    pack_fused<<<MB_CNT * NKT + 64 * NKT, 256, 0, stream>>>(X, W, Apk, Wpk);
    rbf_gemm_d<<<8192, 256, 0, stream>>>(Apk, Wpk, b, out);
  } else {
    rbf_gemm_nows<<<8192, 256, 0, stream>>>(X, W, b, out);
  }
}

// Round 9
// 376.037 us; speedup vs baseline: 1.0951x; 1.0951x over previous
//
#include <hip/hip_runtime.h>

typedef __bf16 bf16x8 __attribute__((ext_vector_type(8)));
typedef float  f32x4  __attribute__((ext_vector_type(4)));

constexpr int M_ROWS = 65536;
constexpr int N_COLS = 2048;
constexpr int K_DIM  = 512;
constexpr int NKT    = 16;             // K-steps of 32
constexpr int MB2    = 256;            // M / 256
constexpr int NB2    = 8;              // N / 256
// packed tile (mb|nb, kt): 16384 ushorts = 32 KB, unit-split [U0 16K][U1 16K]
constexpr size_t APK_USHORTS = (size_t)MB2 * NKT * 16384;  // 128 MiB
constexpr size_t WPK_USHORTS = (size_t)NB2 * NKT * 16384;  //   4 MiB

__device__ __forceinline__ unsigned short f2bf(float f){
  unsigned int u = __float_as_uint(f);
  u += 0x7FFFu + ((u >> 16) & 1u);     // RNE
  return (unsigned short)(u >> 16);
}
__device__ __forceinline__ float bf2f(unsigned short h){
  return __uint_as_float(((unsigned int)h) << 16);
}
__device__ __forceinline__ void split4(const float4& v, ushort4& h, ushort4& l){
  h.x = f2bf(v.x); l.x = f2bf(v.x - bf2f(h.x));
  h.y = f2bf(v.y); l.y = f2bf(v.y - bf2f(h.y));
  h.z = f2bf(v.z); l.z = f2bf(v.z - bf2f(h.z));
  h.w = f2bf(v.w); l.w = f2bf(v.w - bf2f(h.w));
}
__device__ __forceinline__ void split4v(const f32x4& v, ushort4& h, ushort4& l){
  h.x = f2bf(v.x); l.x = f2bf(v.x - bf2f(h.x));
  h.y = f2bf(v.y); l.y = f2bf(v.y - bf2f(h.y));
  h.z = f2bf(v.z); l.z = f2bf(v.z - bf2f(h.z));
  h.w = f2bf(v.w); l.w = f2bf(v.w - bf2f(h.w));
}

__device__ __forceinline__ void gl_lds16(const void* g, void* l){
  __builtin_amdgcn_global_load_lds(
      (const __attribute__((address_space(1))) unsigned int*)g,
      (__attribute__((address_space(3))) unsigned int*)l, 16, 0, 0);
}

constexpr float INV2PI = 0.15915494309189535f;
__device__ __forceinline__ float cos_scaled(float v){
  float rev = v * INV2PI;
  rev -= floorf(rev);                   // [0,1) revolutions for v_cos
  return 0.03125f * __builtin_amdgcn_cosf(rev);
}

// ============ fused prepass: X->Apk (4096 blocks) + W->Wpk (1024) ===========
// A frag (i=0..15, hi/lo) of tile (mb,kt): unit u=(i>>2)&1, slot s=(i&3)+4*(i>>3)
//   ush off = u*8192 + s*1024 + h*512 + (q*16 + r)*8 + half*4
//   (row = mb*256 + i*16 + r, k = kt*32 + q*8 .. +7)
// B frag (jj=0..15, hi/lo) of tile (nb,kt): unit jj>>3, slot jj&7; same inner.
//   col-perm: jj = wc*4 + j holds col nb*256 + wc*64 + fc*4 + j at lane fc.
__global__ void pack_fused(const float* __restrict__ X, const float* __restrict__ W,
                           unsigned short* __restrict__ Apk,
                           unsigned short* __restrict__ Wpk){
  __shared__ __align__(16) unsigned short lds[16384];
  const int b = blockIdx.x, t = threadIdx.x;
  if (b < MB2 * NKT){
    const int mb = b >> 4, kt = b & 15;
    const float* src = X + (size_t)mb * 256 * K_DIM + kt * 32;
    const int fq = t & 7, r0 = t >> 3;
    #pragma unroll
    for (int it = 0; it < 8; ++it){
      int row = r0 + it * 32;
      f32x4 v = __builtin_nontemporal_load(
          reinterpret_cast<const f32x4*>(src + (size_t)row * K_DIM + fq * 4));
      ushort4 h, l; split4v(v, h, l);
      int i = row >> 4, r = row & 15, q = fq >> 1, half = fq & 1;
      int u = (i >> 2) & 1, s = (i & 3) + 4 * (i >> 3);
      int base = u * 8192 + s * 1024 + (q * 16 + r) * 8 + half * 4;
      *reinterpret_cast<ushort4*>(lds + base)       = h;
      *reinterpret_cast<ushort4*>(lds + base + 512) = l;
    }
    __syncthreads();
    unsigned short* dst = Apk + ((size_t)mb * NKT + kt) * 16384;
    #pragma unroll
    for (int it = 0; it < 8; ++it){
      int c = t + it * 256;
      *reinterpret_cast<int4*>(dst + c * 8) = *reinterpret_cast<const int4*>(lds + c * 8);
    }
  } else {
    // W patch: 32 cols x 32 k.  n0 = nbx*32, k0 = kt*32.
    const int b2 = b - MB2 * NKT;
    const int nbx = b2 & 63, kt = b2 >> 6;
    const int n0 = nbx * 32;
    const int nb = nbx >> 3;                 // 256-col Wpk block
    float (*tf)[33] = reinterpret_cast<float(*)[33]>(lds);
    int tx = t & 31, ty = t >> 5;
    #pragma unroll
    for (int rr = 0; rr < 4; ++rr)
      tf[ty + rr*8][tx] = W[(size_t)(kt * 32 + ty + rr*8) * N_COLS + n0 + tx];
    __syncthreads();
    unsigned short* dst = Wpk + ((size_t)nb * NKT + kt) * 16384;
    const int q = tx >> 3, ko = tx & 7;
    #pragma unroll
    for (int rr = 0; rr < 4; ++rr){
      int nl = ty + rr*8;                    // local col 0..31
      float vv = tf[tx][nl];                 // W[k0+tx][n0+nl]
      unsigned short hh = f2bf(vv);
      unsigned short ll = f2bf(vv - bf2f(hh));
      int ng = (nbx & 7) * 32 + nl;          // col within 256-block
      int wc = ng >> 6, rem = ng & 63;
      int j = rem & 3, fc = rem >> 2;
      int jj = wc * 4 + j;
      int e = (jj >> 3) * 8192 + (jj & 7) * 1024 + (q * 16 + fc) * 8 + ko;
      dst[e] = hh; dst[e + 512] = ll;
    }
  }
}

// ============ main GEMM + cos epilogue: 256^2, 4-phase counted-vmcnt ========
#define MFMA_(a,b,c) __builtin_amdgcn_mfma_f32_16x16x32_bf16(a,b,c,0,0,0)

__launch_bounds__(512, 1)
__global__ void rbf_gemm_8p(const unsigned short* __restrict__ Apk,
                            const unsigned short* __restrict__ Wpk,
                            const float* __restrict__ bvec,
                            float* __restrict__ out){
  // LDS 128 KB: Aslot0 @0, Aslot1 @32K, Bslot0 @64K, Bslot1 @96K
  __shared__ __align__(16) unsigned short smem[65536];

  int orig = blockIdx.x;                       // 2048 blocks, 2048 % 8 == 0
  int wgid = (orig & 7) * 256 + (orig >> 3);   // bijective XCD swizzle
  int mb = wgid >> 3, nb = wgid & 7;

  int tid = threadIdx.x, lane = tid & 63, wid = tid >> 6;
  int wr = wid >> 2, wc = wid & 3;
  int r = lane & 15, g = lane >> 4;

  const char* abase = (const char*)(Apk + (size_t)mb * NKT * 16384);
  const char* bbase = (const char*)(Wpk + (size_t)nb * NKT * 16384);
  char* lds = (char*)smem;

  f32x4 acc[8][4];
  #pragma unroll
  for (int i = 0; i < 8; ++i)
    #pragma unroll
    for (int j = 0; j < 4; ++j) acc[i][j] = (f32x4){0.f, 0.f, 0.f, 0.f};

  // ---- stage helpers: one 16 KB unit = 2 block-wide gl_lds ----
  #define STAGE_A(kt_, u_) { \
    const char* s_ = abase + (size_t)(kt_) * 32768 + (u_) * 16384 + tid * 16; \
    char* d_ = lds + (((kt_) & 1) * 32768) + (u_) * 16384 + tid * 16; \
    gl_lds16(s_, d_); gl_lds16(s_ + 8192, d_ + 8192); }
  #define STAGE_B(kt_, u_) { \
    const char* s_ = bbase + (size_t)(kt_) * 32768 + (u_) * 16384 + tid * 16; \
    char* d_ = lds + 65536 + (((kt_) & 1) * 32768) + (u_) * 16384 + tid * 16; \
    gl_lds16(s_, d_); gl_lds16(s_ + 8192, d_ + 8192); }

  #define LOAD_A(AS_, p_) { \
    int oa0_ = ((p_) >> 1) * 16384 + (((2*(p_)) & 3) + 4 * wr) * 2048 + lane * 16; \
    int oa1_ = ((p_) >> 1) * 16384 + (((2*(p_) + 1) & 3) + 4 * wr) * 2048 + lane * 16; \
    a0h = *reinterpret_cast<const bf16x8*>((AS_) + oa0_); \
    a0l = *reinterpret_cast<const bf16x8*>((AS_) + oa0_ + 1024); \
    a1h = *reinterpret_cast<const bf16x8*>((AS_) + oa1_); \
    a1l = *reinterpret_cast<const bf16x8*>((AS_) + oa1_ + 1024); }

  #define MFMA_P(p_) { \
    _Pragma("unroll") \
    for (int j = 0; j < 4; ++j){ \
      acc[2*(p_)][j]   = MFMA_(a0h, Bh[j], acc[2*(p_)][j]); \
      acc[2*(p_)+1][j] = MFMA_(a1h, Bh[j], acc[2*(p_)+1][j]); \
      acc[2*(p_)][j]   = MFMA_(a0l, Bh[j], acc[2*(p_)][j]); \
      acc[2*(p_)+1][j] = MFMA_(a1l, Bh[j], acc[2*(p_)+1][j]); \
      acc[2*(p_)][j]   = MFMA_(a0h, Bl[j], acc[2*(p_)][j]); \
      acc[2*(p_)+1][j] = MFMA_(a1h, Bl[j], acc[2*(p_)+1][j]); \
    } }

  #define SBAR() __builtin_amdgcn_s_barrier()
  #define LGKM0() { asm volatile("s_waitcnt lgkmcnt(0)" ::: "memory"); \
                    __builtin_amdgcn_sched_barrier(0); }

  // ---- prologue: prime tile 0 (issue order = steady-state order) ----
  STAGE_B(0, 0); STAGE_B(0, 1); STAGE_A(0, 0); STAGE_A(0, 1);
  asm volatile("s_waitcnt vmcnt(2)" ::: "memory");   // B0,B1,A0 landed; A1 in flight
  SBAR();

  bf16x8 a0h, a0l, a1h, a1l;

  #pragma unroll 1
  for (int t = 0; t < NKT - 1; ++t){
    const int c = t & 1;
    const char* AS = lds + c * 32768;
    const char* BS = lds + 65536 + c * 32768;

    // ---------------- P0: B frags + A{0,1}; stage BH0(t+1) ----------------
    bf16x8 Bh[4], Bl[4];
    #pragma unroll
    for (int j = 0; j < 4; ++j){
      int ob = ((wc >> 1) * 16384) + (((wc & 1) * 4 + j) * 2048) + lane * 16;
      Bh[j] = *reinterpret_cast<const bf16x8*>(BS + ob);
      Bl[j] = *reinterpret_cast<const bf16x8*>(BS + ob + 1024);
    }
    LOAD_A(AS, 0);
    STAGE_B(t + 1, 0);
    SBAR(); LGKM0();
    __builtin_amdgcn_s_setprio(1); MFMA_P(0); __builtin_amdgcn_s_setprio(0);
    SBAR();
    // ---------------- P1: A{2,3}; stage BH1(t+1); gate AH1(t) -------------
    LOAD_A(AS, 1);
    STAGE_B(t + 1, 1);
    SBAR(); LGKM0();
    __builtin_amdgcn_s_setprio(1); MFMA_P(1); __builtin_amdgcn_s_setprio(0);
    asm volatile("s_waitcnt vmcnt(4)" ::: "memory");  // AH1(t) landed (4 newer ok)
    SBAR();
    // ---------------- P2: A{4,5}; stage AH0(t+1) --------------------------
    LOAD_A(AS, 2);
    STAGE_A(t + 1, 0);
    SBAR(); LGKM0();
    __builtin_amdgcn_s_setprio(1); MFMA_P(2); __builtin_amdgcn_s_setprio(0);
    SBAR();
    // ---------------- P3: A{6,7}; stage AH1(t+1); gate tile t+1 -----------
    LOAD_A(AS, 3);
    STAGE_A(t + 1, 1);
    SBAR(); LGKM0();
    __builtin_amdgcn_s_setprio(1); MFMA_P(3); __builtin_amdgcn_s_setprio(0);
    asm volatile("s_waitcnt vmcnt(2)" ::: "memory");  // B(t+1)+AH0(t+1) landed
    SBAR();
  }

  // ---- peeled last iteration (t = 15, c = 1): full drain, no stages ----
  {
    asm volatile("s_waitcnt vmcnt(0)" ::: "memory");
    SBAR();                                   // all waves' loads landed
    const char* AS = lds + 32768;
    const char* BS = lds + 65536 + 32768;
    bf16x8 Bh[4], Bl[4];
    #pragma unroll
    for (int j = 0; j < 4; ++j){
      int ob = ((wc >> 1) * 16384) + (((wc & 1) * 4 + j) * 2048) + lane * 16;
      Bh[j] = *reinterpret_cast<const bf16x8*>(BS + ob);
      Bl[j] = *reinterpret_cast<const bf16x8*>(BS + ob + 1024);
    }
    LOAD_A(AS, 0); LGKM0(); MFMA_P(0);
    LOAD_A(AS, 1); LGKM0(); MFMA_P(1);
    LOAD_A(AS, 2); LGKM0(); MFMA_P(2);
    LOAD_A(AS, 3); LGKM0(); MFMA_P(3);
  }

  // ---- epilogue: row = mb*256 + wr*128 + i*16 + g*4 + p,
  //               col = nb*256 + wc*64 + r*4 + j  -> NT float4 (full lines) ----
  int colb = nb * 256 + wc * 64 + r * 4;
  f32x4 bv = *reinterpret_cast<const f32x4*>(bvec + colb);
  #pragma unroll
  for (int i = 0; i < 8; ++i){
    #pragma unroll
    for (int p = 0; p < 4; ++p){
      int row = mb * 256 + wr * 128 + i * 16 + g * 4 + p;
      f32x4 o;
      o.x = cos_scaled(acc[i][0][p] + bv.x);
      o.y = cos_scaled(acc[i][1][p] + bv.y);
      o.z = cos_scaled(acc[i][2][p] + bv.z);
      o.w = cos_scaled(acc[i][3][p] + bv.w);
      __builtin_nontemporal_store(o, reinterpret_cast<f32x4*>(out + (size_t)row * N_COLS + colb));
    }
  }
}

// ================= fallback (no workspace): 16x16 path ======================
constexpr int BM = 128, BN = 128;
constexpr int LDSK = 40;
constexpr int SEC  = 128 * LDSK;
__launch_bounds__(256, 2)
__global__ void rbf_gemm_nows(const float* __restrict__ X, const float* __restrict__ W,
                              const float* __restrict__ bvec, float* __restrict__ out){
  __shared__ __align__(16) unsigned short smem[4 * SEC];
  int orig = blockIdx.x;
  int wgid = (orig & 7) * (int)(gridDim.x >> 3) + (orig >> 3);
  int mb = wgid >> 4, nb = wgid & 15;
  int m0 = mb * BM, n0 = nb * BN;
  int tid = threadIdx.x, lane = tid & 63, wid = tid >> 6;
  int wm = wid >> 1, wn = wid & 1;
  int r = lane & 15, g = lane >> 4;

  const float* asrc[4]; int alofs[4]; float4 ra[4];
  const float* wsrc[4]; int wnq4[4]; int wkr[4]; float4 rw[4];
  #pragma unroll
  for (int i = 0; i < 4; ++i){
    int c = tid + i * 256;
    int row = c >> 3, q = c & 7;
    asrc[i]  = X + (size_t)(m0 + row) * K_DIM + q * 4;
    alofs[i] = row * LDSK + q * 4;
  }
  #pragma unroll
  for (int i = 0; i < 4; ++i) ra[i] = *reinterpret_cast<const float4*>(asrc[i]);
  #pragma unroll
  for (int i = 0; i < 4; ++i){
    int c = tid + i * 256;
    int kr = c >> 5, nq = c & 31;
    wsrc[i] = W + (size_t)kr * N_COLS + n0 + nq * 4;
    wkr[i] = kr; wnq4[i] = nq * 4;
  }
  #pragma unroll
  for (int i = 0; i < 4; ++i) rw[i] = *reinterpret_cast<const float4*>(wsrc[i]);

  f32x4 acc[4][4];
  f32x4 zero = {0.f, 0.f, 0.f, 0.f};
  #pragma unroll
  for (int i = 0; i < 4; ++i)
    #pragma unroll
    for (int j = 0; j < 4; ++j) acc[i][j] = zero;

  int aoff[4], boff[4];
  #pragma unroll
  for (int i = 0; i < 4; ++i) aoff[i] = (wm*64 + i*16 + r) * LDSK + g * 8;
  #pragma unroll
  for (int j = 0; j < 4; ++j) boff[j] = (wn*64 + j*16 + r) * LDSK + g * 8;

  #pragma unroll 1
  for (int kt = 0; kt < NKT; ++kt){
    __syncthreads();
    #pragma unroll
    for (int i = 0; i < 4; ++i){
      ushort4 h, l;
      split4(ra[i], h, l);
      *reinterpret_cast<ushort4*>(&smem[alofs[i]])       = h;
      *reinterpret_cast<ushort4*>(&smem[SEC + alofs[i]]) = l;
    }
    #pragma unroll
    for (int i = 0; i < 4; ++i){
      float vv[4] = {rw[i].x, rw[i].y, rw[i].z, rw[i].w};
      #pragma unroll
      for (int w2 = 0; w2 < 4; ++w2){
        unsigned short h = f2bf(vv[w2]);
        unsigned short l = f2bf(vv[w2] - bf2f(h));
        int n = wnq4[i] + w2;
        smem[2*SEC + n*LDSK + wkr[i]] = h;
        smem[3*SEC + n*LDSK + wkr[i]] = l;
      }
    }
    if (kt < NKT - 1){
      #pragma unroll
      for (int i = 0; i < 4; ++i)
        ra[i] = *reinterpret_cast<const float4*>(asrc[i] + (kt+1)*32);
      #pragma unroll
      for (int i = 0; i < 4; ++i)
        rw[i] = *reinterpret_cast<const float4*>(wsrc[i] + (size_t)(kt+1)*32*N_COLS);
    }
    __syncthreads();
    bf16x8 ah[4], al[4], bh[4], bl[4];
    #pragma unroll
    for (int i = 0; i < 4; ++i){
      ah[i] = *reinterpret_cast<const bf16x8*>(&smem[aoff[i]]);
      al[i] = *reinterpret_cast<const bf16x8*>(&smem[SEC + aoff[i]]);
    }
    #pragma unroll
    for (int j = 0; j < 4; ++j){
      bh[j] = *reinterpret_cast<const bf16x8*>(&smem[2*SEC + boff[j]]);
      bl[j] = *reinterpret_cast<const bf16x8*>(&smem[3*SEC + boff[j]]);
    }
    #pragma unroll
    for (int i = 0; i < 4; ++i){
      #pragma unroll
      for (int j = 0; j < 4; ++j){
        acc[i][j] = MFMA_(ah[i], bh[j], acc[i][j]);
        acc[i][j] = MFMA_(al[i], bh[j], acc[i][j]);
        acc[i][j] = MFMA_(ah[i], bl[j], acc[i][j]);
      }
    }
  }

  float bvv[4];
  #pragma unroll
  for (int j = 0; j < 4; ++j) bvv[j] = bvec[n0 + wn*64 + j*16 + r];
  #pragma unroll
  for (int i = 0; i < 4; ++i){
    #pragma unroll
    for (int j = 0; j < 4; ++j){
      int col = n0 + wn*64 + j*16 + r;
      #pragma unroll
      for (int p = 0; p < 4; ++p){
        int row = m0 + wm*64 + i*16 + g*4 + p;
        out[(size_t)row * N_COLS + col] = cos_scaled(acc[i][j][p] + bvv[j]);
      }
    }
  }
}

extern "C" void kernel_launch(void* const* d_in, const int* in_sizes, int n_in,
                              void* d_out, int out_size, void* d_ws, size_t ws_size,
                              hipStream_t stream){
  const float* X = (const float*)d_in[0];
  const float* W = (const float*)d_in[1];
  const float* b = (const float*)d_in[2];
  float* out = (float*)d_out;
  unsigned short* ws = (unsigned short*)d_ws;

  const size_t needP = (APK_USHORTS + WPK_USHORTS) * sizeof(unsigned short); // 132 MiB

  if (ws && ws_size >= needP){
    unsigned short* Apk = ws;
    unsigned short* Wpk = ws + APK_USHORTS;
    pack_fused<<<MB2 * NKT + 64 * NKT, 256, 0, stream>>>(X, W, Apk, Wpk);
    rbf_gemm_8p<<<2048, 512, 0, stream>>>(Apk, Wpk, b, out);
  } else {
    rbf_gemm_nows<<<8192, 256, 0, stream>>>(X, W, b, out);
  }
}

// Round 10
// 315.035 us; speedup vs baseline: 1.3071x; 1.1936x over previous
//
#include <hip/hip_runtime.h>

typedef __bf16 bf16x8 __attribute__((ext_vector_type(8)));
typedef float  f32x4  __attribute__((ext_vector_type(4)));
typedef int    i32x4  __attribute__((ext_vector_type(4)));
typedef char   c16    __attribute__((ext_vector_type(16)));

constexpr int M_ROWS = 65536;
constexpr int N_COLS = 2048;
constexpr int K_DIM  = 512;
constexpr int NKQ    = 8;              // K-steps of 64 (i8 path)
constexpr int MBQ    = 512;            // 128-row tiles
constexpr int NBQ    = 16;             // 128-col tiles

// ws layout: sX 65536 f | sW 2048 f | AQ 64 MiB | WQ 2 MiB
constexpr size_t AQ_OFF  = (65536 + 2048) * 4;          // 270336 B (16-aligned)
constexpr size_t AQ_SZ   = (size_t)MBQ * NKQ * 16384;   // 67108864
constexpr size_t WQ_OFF  = AQ_OFF + AQ_SZ;
constexpr size_t WQ_SZ   = (size_t)NBQ * NKQ * 16384;   // 2097152
constexpr size_t NEEDQ   = WQ_OFF + WQ_SZ;

__device__ __forceinline__ unsigned short f2bf(float f){
  unsigned int u = __float_as_uint(f);
  u += 0x7FFFu + ((u >> 16) & 1u);
  return (unsigned short)(u >> 16);
}
__device__ __forceinline__ float bf2f(unsigned short h){
  return __uint_as_float(((unsigned int)h) << 16);
}
__device__ __forceinline__ void split4(const float4& v, ushort4& h, ushort4& l){
  h.x = f2bf(v.x); l.x = f2bf(v.x - bf2f(h.x));
  h.y = f2bf(v.y); l.y = f2bf(v.y - bf2f(h.y));
  h.z = f2bf(v.z); l.z = f2bf(v.z - bf2f(h.z));
  h.w = f2bf(v.w); l.w = f2bf(v.w - bf2f(h.w));
}

__device__ __forceinline__ void gl_lds16(const void* g, void* l){
  __builtin_amdgcn_global_load_lds(
      (const __attribute__((address_space(1))) unsigned int*)g,
      (__attribute__((address_space(3))) unsigned int*)l, 16, 0, 0);
}

constexpr float INV2PI = 0.15915494309189535f;
__device__ __forceinline__ float cos_scaled(float v){
  float rev = v * INV2PI;
  rev -= floorf(rev);
  return 0.03125f * __builtin_amdgcn_cosf(rev);
}

// quantize one float given inv = 1/s: x1 = rint(x*inv), x2 = rint((x*inv-x1)*256)
__device__ __forceinline__ void q2(float x, float inv, char& o1, char& o2){
  float t1 = x * inv;
  float r1 = rintf(t1);
  float r2 = fminf(rintf((t1 - r1) * 256.0f), 127.0f);
  o1 = (char)(int)r1;
  o2 = (char)(int)r2;
}

// ============ prepass 1: X -> AQ (fused rowmax + 2-split i8, frag-linear) ===
// AQ tile (mb,kt): [x1 8192 B][x2 8192 B]; chunk c = i*64 + lane,
// lane = q*16 + r <-> row mb*128+i*16+r, k = kt*64 + q*16 .. +15 (16 i8).
__global__ void pack_xq(const float* __restrict__ X, char* __restrict__ AQ,
                        float* __restrict__ sXo){
  const int bid = blockIdx.x;          // 2048 blocks x 32 rows
  const int t = threadIdx.x;
  const int rl = t >> 3, seg = t & 7;  // seg == kt
  const int grow = bid * 32 + rl;
  const float* src = X + (size_t)grow * K_DIM + seg * 64;
  f32x4 v[16];
  #pragma unroll
  for (int i = 0; i < 16; ++i)
    v[i] = __builtin_nontemporal_load(reinterpret_cast<const f32x4*>(src) + i);
  float m = 0.f;
  #pragma unroll
  for (int i = 0; i < 16; ++i)
    m = fmaxf(m, fmaxf(fmaxf(fabsf(v[i].x), fabsf(v[i].y)),
                       fmaxf(fabsf(v[i].z), fabsf(v[i].w))));
  m = fmaxf(m, __shfl_xor(m, 1));
  m = fmaxf(m, __shfl_xor(m, 2));
  m = fmaxf(m, __shfl_xor(m, 4));      // full-row max across 8 segs
  m = fmaxf(m, 1e-10f);
  if (seg == 0) sXo[grow] = m * (1.0f / 127.0f);
  const float inv = 127.0f / m;

  const int mb = bid >> 2;
  const int rowt = (bid & 3) * 32 + rl;
  const int i_ = rowt >> 4, r_ = rowt & 15;
  char* tb = AQ + (size_t)(mb * NKQ + seg) * 16384;
  #pragma unroll
  for (int q = 0; q < 4; ++q){
    c16 o1, o2;
    #pragma unroll
    for (int u = 0; u < 4; ++u){
      f32x4 xv = v[q * 4 + u];
      #pragma unroll
      for (int w = 0; w < 4; ++w){
        char a, b; q2(xv[w], inv, a, b);
        o1[u * 4 + w] = a; o2[u * 4 + w] = b;
      }
    }
    int c = i_ * 64 + q * 16 + r_;
    *reinterpret_cast<c16*>(tb + c * 16)        = o1;
    *reinterpret_cast<c16*>(tb + 8192 + c * 16) = o2;
  }
}

// ============ prepass 2: per-col max of W ===================================
__global__ void scale_w(const float* __restrict__ W, float* __restrict__ sWo){
  __shared__ float red[8][32];
  int t = threadIdx.x, nl = t & 31, kq = t >> 5;
  int n = blockIdx.x * 32 + nl;
  float m = 0.f;
  for (int k = kq * 64; k < kq * 64 + 64; ++k)
    m = fmaxf(m, fabsf(W[(size_t)k * N_COLS + n]));
  red[kq][nl] = m;
  __syncthreads();
  if (kq == 0){
    #pragma unroll
    for (int u = 1; u < 8; ++u) m = fmaxf(m, red[u][nl]);
    sWo[n] = fmaxf(m, 1e-10f) * (1.0f / 127.0f);
  }
}

// ============ prepass 3: W -> WQ (transpose + 2-split i8 + col-perm) ========
// WQ tile (nb,kt): [w1 8192][w2 8192]; chunk c = jj*64 + q*16 + fc holds
// col nb*128 + (jj>>2)*64 + fc*4 + (jj&3), k = kt*64 + q*16 .. +15.
__global__ void pack_wq(const float* __restrict__ W, const float* __restrict__ sW,
                        char* __restrict__ WQ){
  __shared__ float tf[64][132];
  const int nb = blockIdx.x, kt = blockIdx.y, t = threadIdx.x;
  const int kr = t >> 2, nq = t & 3;
  #pragma unroll
  for (int it = 0; it < 8; ++it){
    f32x4 v4 = *reinterpret_cast<const f32x4*>(
        W + (size_t)(kt * 64 + kr) * N_COLS + nb * 128 + nq * 32 + it * 4);
    *reinterpret_cast<f32x4*>(&tf[kr][nq * 32 + it * 4]) = v4;
  }
  __syncthreads();
  char* tb = WQ + (size_t)(nb * NKQ + kt) * 16384;
  #pragma unroll
  for (int cc = 0; cc < 2; ++cc){
    int c = t + cc * 256;
    int jj = c >> 6, q = (c >> 4) & 3, fc = c & 15;
    int col_local = (jj >> 2) * 64 + fc * 4 + (jj & 3);
    float inv = 1.0f / sW[nb * 128 + col_local];   // = 127/colmax
    c16 o1, o2;
    #pragma unroll
    for (int e = 0; e < 16; ++e){
      char a, b; q2(tf[q * 16 + e][col_local], inv, a, b);
      o1[e] = a; o2[e] = b;
    }
    *reinterpret_cast<c16*>(tb + c * 16)        = o1;
    *reinterpret_cast<c16*>(tb + 8192 + c * 16) = o2;
  }
}

// ============ main GEMM (i8 Ozaki 3-product) + cos epilogue =================
#define MFMAI(a,b,c) __builtin_amdgcn_mfma_i32_16x16x64_i8(a,b,c,0,0,0)

__launch_bounds__(256, 2)
__global__ void rbf_gemm_i8(const char* __restrict__ AQ, const char* __restrict__ WQ,
                            const float* __restrict__ sX, const float* __restrict__ sW,
                            const float* __restrict__ bvec, float* __restrict__ out){
  __shared__ __align__(16) char smem[2 * 16384];   // B dbuf (x1|x2 planes each)

  int orig = blockIdx.x;                        // 8192, % 8 == 0
  int wgid = (orig & 7) * 1024 + (orig >> 3);   // bijective XCD swizzle
  int mb = wgid >> 4, nb = wgid & 15;
  int m0 = mb * 128, n0 = nb * 128;

  int tid = threadIdx.x, lane = tid & 63, wid = tid >> 6;
  int wm = wid >> 1, wn = wid & 1;
  int r = lane & 15, g = lane >> 4;

  const char* abase = AQ + (size_t)mb * NKQ * 16384;
  const char* bbase = WQ + (size_t)nb * NKQ * 16384;
  const int bsoff = wid * 1024 + lane * 16;
  const int bdoff = wid * 1024;

  int aoffs[4], boffs[4];
  #pragma unroll
  for (int i = 0; i < 4; ++i) aoffs[i] = (wm * 4 + i) * 1024 + lane * 16;
  #pragma unroll
  for (int j = 0; j < 4; ++j) boffs[j] = (wn * 4 + j) * 1024 + lane * 16;

  i32x4 accm[4][4], accc[4][4];
  #pragma unroll
  for (int i = 0; i < 4; ++i)
    #pragma unroll
    for (int j = 0; j < 4; ++j){
      accm[i][j] = (i32x4){0,0,0,0};
      accc[i][j] = (i32x4){0,0,0,0};
    }

  i32x4 a1A[4], a2A[4], a1B[4], a2B[4];

  // prologue: A[0] -> set A, B[0] -> buf0
  #pragma unroll
  for (int i = 0; i < 4; ++i){
    a1A[i] = *reinterpret_cast<const i32x4*>(abase + aoffs[i]);
    a2A[i] = *reinterpret_cast<const i32x4*>(abase + 8192 + aoffs[i]);
  }
  #pragma unroll
  for (int it = 0; it < 4; ++it)
    gl_lds16(bbase + it * 4096 + bsoff, smem + it * 4096 + bdoff);
  __syncthreads();

  #pragma unroll 1
  for (int kt = 0; kt < NKQ; kt += 2){
    { // even: compute (setA, buf0); prefetch kt+1 -> (setB, buf1)
      const char* bb = bbase + (size_t)(kt + 1) * 16384;
      #pragma unroll
      for (int it = 0; it < 4; ++it)
        gl_lds16(bb + it * 4096 + bsoff, smem + 16384 + it * 4096 + bdoff);
      const char* ab = abase + (size_t)(kt + 1) * 16384;
      #pragma unroll
      for (int i = 0; i < 4; ++i){
        a1B[i] = *reinterpret_cast<const i32x4*>(ab + aoffs[i]);
        a2B[i] = *reinterpret_cast<const i32x4*>(ab + 8192 + aoffs[i]);
      }
      const char* SB = smem;
      #pragma unroll
      for (int j = 0; j < 4; ++j){
        i32x4 b1 = *reinterpret_cast<const i32x4*>(SB + boffs[j]);
        i32x4 b2 = *reinterpret_cast<const i32x4*>(SB + 8192 + boffs[j]);
        #pragma unroll
        for (int i = 0; i < 4; ++i){
          accm[i][j] = MFMAI(a1A[i], b1, accm[i][j]);
          accc[i][j] = MFMAI(a1A[i], b2, accc[i][j]);
          accc[i][j] = MFMAI(a2A[i], b1, accc[i][j]);
        }
      }
      __syncthreads();
    }
    { // odd: compute (setB, buf1); prefetch kt+2 -> (setA, buf0)
      if (kt + 2 < NKQ){
        const char* bb = bbase + (size_t)(kt + 2) * 16384;
        #pragma unroll
        for (int it = 0; it < 4; ++it)
          gl_lds16(bb + it * 4096 + bsoff, smem + it * 4096 + bdoff);
        const char* ab = abase + (size_t)(kt + 2) * 16384;
        #pragma unroll
        for (int i = 0; i < 4; ++i){
          a1A[i] = *reinterpret_cast<const i32x4*>(ab + aoffs[i]);
          a2A[i] = *reinterpret_cast<const i32x4*>(ab + 8192 + aoffs[i]);
        }
      }
      const char* SB = smem + 16384;
      #pragma unroll
      for (int j = 0; j < 4; ++j){
        i32x4 b1 = *reinterpret_cast<const i32x4*>(SB + boffs[j]);
        i32x4 b2 = *reinterpret_cast<const i32x4*>(SB + 8192 + boffs[j]);
        #pragma unroll
        for (int i = 0; i < 4; ++i){
          accm[i][j] = MFMAI(a1B[i], b1, accm[i][j]);
          accc[i][j] = MFMAI(a1B[i], b2, accc[i][j]);
          accc[i][j] = MFMAI(a2B[i], b1, accc[i][j]);
        }
      }
      __syncthreads();
    }
  }

  // epilogue: arg = sX[row]*sW[col]*(main + cross/256) + b[col]
  // row = m0 + wm*64 + i*16 + g*4 + p, col = n0 + wn*64 + r*4 + j
  int colb = n0 + wn * 64 + r * 4;
  f32x4 sw4 = *reinterpret_cast<const f32x4*>(sW + colb);
  f32x4 bv  = *reinterpret_cast<const f32x4*>(bvec + colb);
  #pragma unroll
  for (int i = 0; i < 4; ++i){
    int rowb = m0 + wm * 64 + i * 16 + g * 4;
    f32x4 sx4 = *reinterpret_cast<const f32x4*>(sX + rowb);
    #pragma unroll
    for (int p = 0; p < 4; ++p){
      float sx = sx4[p];
      f32x4 o;
      o.x = cos_scaled(fmaf(sx * sw4.x,
              (float)accm[i][0][p] + (float)accc[i][0][p] * 0.00390625f, bv.x));
      o.y = cos_scaled(fmaf(sx * sw4.y,
              (float)accm[i][1][p] + (float)accc[i][1][p] * 0.00390625f, bv.y));
      o.z = cos_scaled(fmaf(sx * sw4.z,
              (float)accm[i][2][p] + (float)accc[i][2][p] * 0.00390625f, bv.z));
      o.w = cos_scaled(fmaf(sx * sw4.w,
              (float)accm[i][3][p] + (float)accc[i][3][p] * 0.00390625f, bv.w));
      __builtin_nontemporal_store(o,
          reinterpret_cast<f32x4*>(out + (size_t)(rowb + p) * N_COLS + colb));
    }
  }
}

// ================= fallback (no workspace): bf16 3-product ==================
#define MFMA_(a,b,c) __builtin_amdgcn_mfma_f32_16x16x32_bf16(a,b,c,0,0,0)
constexpr int LDSK = 40;
constexpr int SEC  = 128 * LDSK;
__launch_bounds__(256, 2)
__global__ void rbf_gemm_nows(const float* __restrict__ X, const float* __restrict__ W,
                              const float* __restrict__ bvec, float* __restrict__ out){
  __shared__ __align__(16) unsigned short smem[4 * SEC];
  int orig = blockIdx.x;
  int wgid = (orig & 7) * (int)(gridDim.x >> 3) + (orig >> 3);
  int mb = wgid >> 4, nb = wgid & 15;
  int m0 = mb * 128, n0 = nb * 128;
  int tid = threadIdx.x, lane = tid & 63, wid = tid >> 6;
  int wm = wid >> 1, wn = wid & 1;
  int r = lane & 15, g = lane >> 4;

  const float* asrc[4]; int alofs[4]; float4 ra[4];
  const float* wsrc[4]; int wnq4[4]; int wkr[4]; float4 rw[4];
  #pragma unroll
  for (int i = 0; i < 4; ++i){
    int c = tid + i * 256;
    int row = c >> 3, q = c & 7;
    asrc[i]  = X + (size_t)(m0 + row) * K_DIM + q * 4;
    alofs[i] = row * LDSK + q * 4;
  }
  #pragma unroll
  for (int i = 0; i < 4; ++i) ra[i] = *reinterpret_cast<const float4*>(asrc[i]);
  #pragma unroll
  for (int i = 0; i < 4; ++i){
    int c = tid + i * 256;
    int kr = c >> 5, nq = c & 31;
    wsrc[i] = W + (size_t)kr * N_COLS + n0 + nq * 4;
    wkr[i] = kr; wnq4[i] = nq * 4;
  }
  #pragma unroll
  for (int i = 0; i < 4; ++i) rw[i] = *reinterpret_cast<const float4*>(wsrc[i]);

  f32x4 acc[4][4];
  #pragma unroll
  for (int i = 0; i < 4; ++i)
    #pragma unroll
    for (int j = 0; j < 4; ++j) acc[i][j] = (f32x4){0.f,0.f,0.f,0.f};

  int aoff[4], boff[4];
  #pragma unroll
  for (int i = 0; i < 4; ++i) aoff[i] = (wm*64 + i*16 + r) * LDSK + g * 8;
  #pragma unroll
  for (int j = 0; j < 4; ++j) boff[j] = (wn*64 + j*16 + r) * LDSK + g * 8;

  #pragma unroll 1
  for (int kt = 0; kt < 16; ++kt){
    __syncthreads();
    #pragma unroll
    for (int i = 0; i < 4; ++i){
      ushort4 h, l;
      split4(ra[i], h, l);
      *reinterpret_cast<ushort4*>(&smem[alofs[i]])       = h;
      *reinterpret_cast<ushort4*>(&smem[SEC + alofs[i]]) = l;
    }
    #pragma unroll
    for (int i = 0; i < 4; ++i){
      float vv[4] = {rw[i].x, rw[i].y, rw[i].z, rw[i].w};
      #pragma unroll
      for (int w2 = 0; w2 < 4; ++w2){
        unsigned short h = f2bf(vv[w2]);
        unsigned short l = f2bf(vv[w2] - bf2f(h));
        int n = wnq4[i] + w2;
        smem[2*SEC + n*LDSK + wkr[i]] = h;
        smem[3*SEC + n*LDSK + wkr[i]] = l;
      }
    }
    if (kt < 15){
      #pragma unroll
      for (int i = 0; i < 4; ++i)
        ra[i] = *reinterpret_cast<const float4*>(asrc[i] + (kt+1)*32);
      #pragma unroll
      for (int i = 0; i < 4; ++i)
        rw[i] = *reinterpret_cast<const float4*>(wsrc[i] + (size_t)(kt+1)*32*N_COLS);
    }
    __syncthreads();
    bf16x8 ah[4], al[4], bh[4], bl[4];
    #pragma unroll
    for (int i = 0; i < 4; ++i){
      ah[i] = *reinterpret_cast<const bf16x8*>(&smem[aoff[i]]);
      al[i] = *reinterpret_cast<const bf16x8*>(&smem[SEC + aoff[i]]);
    }
    #pragma unroll
    for (int j = 0; j < 4; ++j){
      bh[j] = *reinterpret_cast<const bf16x8*>(&smem[2*SEC + boff[j]]);
      bl[j] = *reinterpret_cast<const bf16x8*>(&smem[3*SEC + boff[j]]);
    }
    #pragma unroll
    for (int i = 0; i < 4; ++i){
      #pragma unroll
      for (int j = 0; j < 4; ++j){
        acc[i][j] = MFMA_(ah[i], bh[j], acc[i][j]);
        acc[i][j] = MFMA_(al[i], bh[j], acc[i][j]);
        acc[i][j] = MFMA_(ah[i], bl[j], acc[i][j]);
      }
    }
  }

  float bvv[4];
  #pragma unroll
  for (int j = 0; j < 4; ++j) bvv[j] = bvec[n0 + wn*64 + j*16 + r];
  #pragma unroll
  for (int i = 0; i < 4; ++i){
    #pragma unroll
    for (int j = 0; j < 4; ++j){
      int col = n0 + wn*64 + j*16 + r;
      #pragma unroll
      for (int p = 0; p < 4; ++p){
        int row = m0 + wm*64 + i*16 + g*4 + p;
        out[(size_t)row * N_COLS + col] = cos_scaled(acc[i][j][p] + bvv[j]);
      }
    }
  }
}

extern "C" void kernel_launch(void* const* d_in, const int* in_sizes, int n_in,
                              void* d_out, int out_size, void* d_ws, size_t ws_size,
                              hipStream_t stream){
  const float* X = (const float*)d_in[0];
  const float* W = (const float*)d_in[1];
  const float* b = (const float*)d_in[2];
  float* out = (float*)d_out;
  char* ws = (char*)d_ws;

  if (ws && ws_size >= NEEDQ){
    float* sX = (float*)ws;
    float* sW = (float*)(ws + 65536 * 4);
    char*  AQ = ws + AQ_OFF;
    char*  WQ = ws + WQ_OFF;
    pack_xq<<<2048, 256, 0, stream>>>(X, AQ, sX);
    scale_w<<<64, 256, 0, stream>>>(W, sW);
    pack_wq<<<dim3(NBQ, NKQ), 256, 0, stream>>>(W, sW, WQ);
    rbf_gemm_i8<<<8192, 256, 0, stream>>>(AQ, WQ, sX, sW, b, out);
  } else {
    rbf_gemm_nows<<<8192, 256, 0, stream>>>(X, W, b, out);
  }
}